// Round 11
// baseline (220.793 us; speedup 1.0000x reference)
//
#include <hip/hip_runtime.h>
#include <stdint.h>

// ProposalLayerSoft: 3x3x3 NMS + per-batch top-10 + coord epilogue.
// Input:  d_in[0] = root_cubes f32 [B=32, X=128, Y=128, Z=64]
// Output: d_out   = f32 [B, 10, 5] = (x,y,z, valid-1, score)
// ws: 32*40*10*8 = 102,400 bytes of per-block top-10 keys.
//
// Round-10 orientation (y-coalesced) + z-SPLIT for real prefetching:
// lane = zq*16 + yi; thread holds an 8-z stripe (2 float4 + 1 boundary
// dword) of column gy = y0+yi; two sequential z-passes (z 0..31, 32..63).
// Rationale: with 16-z stripes the live set (~96 floats) forced the
// compiler to sink "prefetch" loads to their uses (VGPR_Count 44-48 all
// rounds => pipeline destroyed, VALUBusy ~25%). 8-z stripes halve plane
// cost: 4 v-planes (prefetch distance 2) + 3 zm-planes = ~85 VGPR, fits
// under lb(256,4)'s 128 cap with the pipeline intact.
// Separable 27-max per pass:
//   z: in-register max3 + 2 shuffles (lane+-16) + boundary dword at the
//      pass seam (z=31/32), edges (z=-1/64) forced -inf
//   y: v_mov_dpp row_shl/shr:1 (row-edge fill only hits yi=0/15 halo)
//   x: rolling 3-plane zm ring, 4-plane v ring, prefetch 2 ahead
// Peaks: ballot+mbcnt compacted append to per-wave LDS list (no atomics).
// NOTE: __launch_bounds__(256,4). (256,5) caused scratch (round 9),
// (256,8) spilled 192 MB (round 6). Do not raise.

#define TPB 256
#define NK 10
#define TY 10                    // y tiles, 14 interior columns each
#define BLOCKS_PER_B (4 * TY)    // grid.y=4 seg-packs x 10 ty = 40
#define WCAP 512                 // per-wave cand cap (mean ~265, +15 sigma)
typedef unsigned long long u64;

__device__ __forceinline__ u64 bfly_max_u64(u64 v) {
#pragma unroll
  for (int off = 1; off < 64; off <<= 1) {
    u64 o = __shfl_xor(v, off, 64);
    v = (o > v) ? o : v;
  }
  return v;
}

// DPP row shifts within 16-lane rows; bound_ctrl=1 -> 0.0f fill at row
// edges (only yi=0/15 halo lanes, never emitted).
__device__ __forceinline__ float dpp_nbr_a(float v) {  // one y-neighbor
  return __int_as_float(__builtin_amdgcn_update_dpp(
      0, __float_as_int(v), 0x101, 0xF, 0xF, true));   // row_shl:1
}
__device__ __forceinline__ float dpp_nbr_b(float v) {  // other y-neighbor
  return __int_as_float(__builtin_amdgcn_update_dpp(
      0, __float_as_int(v), 0x111, 0xF, 0xF, true));   // row_shr:1
}

__global__ __launch_bounds__(TPB, 4) void peaks_topk(
    const float* __restrict__ in, u64* __restrict__ part) {
  __shared__ u64 cand[4][WCAP];  // 16 KB
  __shared__ u64 wtop[4 * NK];
  const int tid = threadIdx.x;
  const int w = tid >> 6, lane = tid & 63;
  const int yi = lane & 15, zq = lane >> 4;
  const int ty = blockIdx.x, b = blockIdx.z;
  const int seg = blockIdx.y * 4 + w;        // 0..15, 8 x-steps each
  const int y0 = ty * 14 - 1;
  const int gy = y0 + yi;
  const int cy = min(127, max(0, gy));       // clamp == dup col: max-safe
  const int x0 = seg * 8;
  const bool emit_ok = (yi >= 1) && (yi <= 14) && (gy <= 127);

  int wcnt = 0;  // wave-uniform candidate count (scalar)

  // ---- one z-pass: z in [p*32, p*32+32), 8-z stripe per lane ----
  auto run_pass = [&](const int p) {
    const int zb = p * 32 + (zq << 3);       // stripe base z
    const float* __restrict__ colz =
        in + ((size_t)b << 20) + ((size_t)cy << 6) + zb;
    const int eo = (p == 0) ? 8 : -1;        // seam dword (always valid z)

    float vb[4][8], ve[4], zmb[3][8];

    auto loadv = [&](int x, float* v, float& e) {
      const int cx = min(127, max(0, x));
      const float* pp = colz + ((size_t)cx << 13);
      float4 a = *(const float4*)pp;
      float4 bq = *(const float4*)(pp + 4);
      v[0] = a.x;  v[1] = a.y;  v[2] = a.z;  v[3] = a.w;
      v[4] = bq.x; v[5] = bq.y; v[6] = bq.z; v[7] = bq.w;
      e = pp[eo];
    };
    // z-stage: stripe-internal max3; stripe boundaries via 2 shuffles
    // (lane+-16 = same yi, zq+-1); pass seam via the extra dword; z=-1
    // and z=64 forced -inf.
    auto zmcalc = [&](const float* v, float e, float* zm) {
      float vl = __shfl_up(v[7], 16, 64);
      float vr = __shfl_down(v[0], 16, 64);
      if (p == 0) {
        vl = (zq == 0) ? -1e30f : vl;        // z=-1
        vr = (zq == 3) ? e : vr;             // z=32 seam
      } else {
        vl = (zq == 0) ? e : vl;             // z=31 seam
        vr = (zq == 3) ? -1e30f : vr;        // z=64
      }
      zm[0] = fmaxf(vl, fmaxf(v[0], v[1]));
#pragma unroll
      for (int j = 1; j < 7; ++j)
        zm[j] = fmaxf(v[j - 1], fmaxf(v[j], v[j + 1]));
      zm[7] = fmaxf(v[6], fmaxf(v[7], vr));
    };

    // plane i (x = x0+i, i in -1..8) lives in vb[(i+1)&3]; zm(i) in
    // zmb[(i+1)%3]. Prologue: planes -1,0,1,2 loaded; zm(-1), zm(0).
    loadv(x0 - 1, vb[0], ve[0]);
    loadv(x0,     vb[1], ve[1]);
    loadv(x0 + 1, vb[2], ve[2]);
    loadv(x0 + 2, vb[3], ve[3]);
    zmcalc(vb[0], ve[0], zmb[0]);
    zmcalc(vb[1], ve[1], zmb[1]);

#pragma unroll
    for (int t = 0; t < 8; ++t) {
      const int x = x0 + t;
      if (t < 6)  // prefetch plane t+3, two iterations ahead of its use
        loadv(x + 3, vb[(t + 4) & 3], ve[(t + 4) & 3]);
      zmcalc(vb[(t + 2) & 3], ve[(t + 2) & 3], zmb[(t + 2) % 3]);
      const float* vC = vb[(t + 1) & 3];
      const float* zmP = zmb[t % 3];
      const float* zmC = zmb[(t + 1) % 3];
      const float* zmN = zmb[(t + 2) % 3];
#pragma unroll
      for (int j = 0; j < 8; ++j) {
        float xm = fmaxf(zmP[j], fmaxf(zmC[j], zmN[j]));
        float l = dpp_nbr_a(xm);         // y-neighbors via DPP (VALU pipe)
        float r = dpp_nbr_b(xm);
        float m27 = fmaxf(xm, fmaxf(l, r));
        float v = vC[j];
        const bool pred = emit_ok && (v >= m27);  // v == 27-max
        u64 mask = __ballot(pred);
        if (pred) {
          unsigned g = ((unsigned)x << 13) | ((unsigned)gy << 6) |
                       (unsigned)(zb + j);
          u64 key = ((u64)__float_as_uint(v) << 32) | (u64)(unsigned)(~g);
          int ofs = __builtin_amdgcn_mbcnt_hi(
              (unsigned)(mask >> 32),
              __builtin_amdgcn_mbcnt_lo((unsigned)mask, 0));
          int slot = wcnt + ofs;
          if (slot < WCAP) cand[w][slot] = key;
        }
        wcnt += (int)__popcll(mask);
      }
    }
  };

  run_pass(0);
  run_pass(1);

  // ---- wave top-10 from LDS list (regs + butterfly, no barriers) ----
  __builtin_amdgcn_s_waitcnt(0);  // drain own-wave LDS writes
  const int count = min(wcnt, WCAP);
  u64 c[WCAP / 64];
#pragma unroll
  for (int i = 0; i < WCAP / 64; ++i) {
    int idx = lane + (i << 6);
    c[i] = (idx < count) ? cand[w][idx] : 0;
  }
  u64 mine = 0;
#pragma unroll 1
  for (int r = 0; r < NK; ++r) {
    u64 best = c[0];
#pragma unroll
    for (int i = 1; i < WCAP / 64; ++i) best = (c[i] > best) ? c[i] : best;
    u64 m = bfly_max_u64(best);
    if (m != 0 && best == m) {  // unique keys: only owner lane matches
#pragma unroll
      for (int i = 0; i < WCAP / 64; ++i)
        if (c[i] == m) c[i] = 0;
    }
    if (lane == r) mine = m;
  }
  if (lane < NK) wtop[w * NK + lane] = mine;
  __syncthreads();

  // ---- block merge 40 -> 10 (wave 0), one barrier total ----
  if (w == 0) {
    u64 c0 = (lane < 4 * NK) ? wtop[lane] : 0;
    u64 mv = 0;
#pragma unroll 1
    for (int r = 0; r < NK; ++r) {
      u64 m = bfly_max_u64(c0);
      if (m != 0 && c0 == m) c0 = 0;
      if (lane == r) mv = m;
    }
    if (lane < NK) {
      const int bi = blockIdx.y * TY + ty;  // 0..39 within batch
      part[((size_t)b * BLOCKS_PER_B + bi) * NK + lane] = mv;
    }
  }
}

// One wave per batch: 400 keys -> 7 regs/lane -> 10 butterfly rounds.
// Zero barriers, zero LDS.
__global__ __launch_bounds__(64) void final_select(
    const u64* __restrict__ part, float* __restrict__ out) {
  const int lane = threadIdx.x & 63;
  const int b = blockIdx.x;
  const int NKEY = BLOCKS_PER_B * NK;  // 400

  const u64* __restrict__ src = part + (size_t)b * NKEY;
  u64 c[7];
#pragma unroll
  for (int i = 0; i < 7; ++i) {
    int idx = lane + (i << 6);
    c[i] = (idx < NKEY) ? src[idx] : 0;
  }
  u64 mine = 0;
#pragma unroll 1
  for (int r = 0; r < NK; ++r) {
    u64 best = c[0];
#pragma unroll
    for (int i = 1; i < 7; ++i) best = (c[i] > best) ? c[i] : best;
    u64 m = bfly_max_u64(best);
    if (m != 0 && best == m) {
#pragma unroll
      for (int i = 0; i < 7; ++i)
        if (c[i] == m) c[i] = 0;
    }
    if (lane == r) mine = m;
  }
  if (lane < NK) {
    float val = 0.0f;
    unsigned g = 0u;
    if (mine != 0) {
      val = __uint_as_float((unsigned)(mine >> 32));
      g = ~((unsigned)mine);
    }
    float fx = (float)(g >> 13) * (8000.0f / 127.0f) - 4000.0f;
    float fy = (float)((g >> 6) & 127u) * (8000.0f / 127.0f) - 4000.0f;
    float fz = (float)(g & 63u) * (2000.0f / 63.0f) - 700.0f;
    float conf = (val > 0.3f) ? 0.0f : -1.0f;
    float* o = out + ((size_t)b * NK + lane) * 5;
    o[0] = fx; o[1] = fy; o[2] = fz; o[3] = conf; o[4] = val;
  }
}

extern "C" void kernel_launch(void* const* d_in, const int* in_sizes, int n_in,
                              void* d_out, int out_size, void* d_ws, size_t ws_size,
                              hipStream_t stream) {
  const float* in = (const float*)d_in[0];
  float* out = (float*)d_out;
  u64* part = (u64*)d_ws;  // 102,400 B used

  const int B = in_sizes[0] >> 20;  // 128*128*64 = 2^20 elements per batch
  dim3 gridA(TY, 4, (unsigned)B);
  peaks_topk<<<gridA, dim3(TPB), 0, stream>>>(in, part);
  final_select<<<dim3((unsigned)B), dim3(64), 0, stream>>>(part, out);
}

// Round 12
// 213.083 us; speedup vs baseline: 1.0362x; 1.0362x over previous
//
#include <hip/hip_runtime.h>
#include <stdint.h>

// ProposalLayerSoft: 3x3x3 NMS + per-batch top-10 + coord epilogue.
// Input:  d_in[0] = root_cubes f32 [B=32, X=128, Y=128, Z=64]
// Output: d_out   = f32 [B, 10, 5] = (x,y,z, valid-1, score)
// ws: 32*40*10*8 = 102,400 bytes of per-block top-10 keys.
//
// Round-10 slab (y-coalesced, lane = zq*16+yi, 16-z stripe, x-sweep) with
// a ROLLED t-loop. Theory: every fully-unrolled variant (rounds 5-11)
// produced a 15-30 KB hot body that thrashes the 32 KB I$ -- explaining
// ~75 us walls with ALL pipes <30% busy, invariant to memory strategy.
// Rolled body ~3 KB. State compression: instead of 3 zm planes keep
// pm[j] = max(zm(x-1), zm(x)) and zmLast[j] = zm(x) -- the 27-max is
// m27 = max(pm, zm(x+1), y-neighbors via DPP). 5x16 live floats.
//   z: in-register max3 + 2 shuffles (lane+-16 stripe boundary)
//   y: v_mov_dpp row_shl/shr:1 (row-edge fill only hits yi=0/15 halo)
//   x: rolled sweep, prefetch plane x+2 into vT at loop top
// Peaks: ballot+mbcnt compacted append to per-wave LDS list (no atomics).
// NOTE: __launch_bounds__(256,4). (256,5) caused scratch (round 9),
// (256,8) spilled 192 MB (round 6). Do not raise.

#define TPB 256
#define NK 10
#define TY 10                    // y tiles, 14 interior columns each
#define BLOCKS_PER_B (4 * TY)    // grid.y=4 seg-packs x 10 ty = 40
#define WCAP 512                 // per-wave cand cap (mean ~265, +15 sigma)
typedef unsigned long long u64;

__device__ __forceinline__ u64 bfly_max_u64(u64 v) {
#pragma unroll
  for (int off = 1; off < 64; off <<= 1) {
    u64 o = __shfl_xor(v, off, 64);
    v = (o > v) ? o : v;
  }
  return v;
}

// DPP row shifts within 16-lane rows; bound_ctrl=1 -> 0.0f fill at row
// edges (only yi=0/15 halo lanes, never emitted).
__device__ __forceinline__ float dpp_nbr_a(float v) {  // one y-neighbor
  return __int_as_float(__builtin_amdgcn_update_dpp(
      0, __float_as_int(v), 0x101, 0xF, 0xF, true));   // row_shl:1
}
__device__ __forceinline__ float dpp_nbr_b(float v) {  // other y-neighbor
  return __int_as_float(__builtin_amdgcn_update_dpp(
      0, __float_as_int(v), 0x111, 0xF, 0xF, true));   // row_shr:1
}

__global__ __launch_bounds__(TPB, 4) void peaks_topk(
    const float* __restrict__ in, u64* __restrict__ part) {
  __shared__ u64 cand[4][WCAP];  // 16 KB
  __shared__ u64 wtop[4 * NK];
  const int tid = threadIdx.x;
  const int w = tid >> 6, lane = tid & 63;
  const int yi = lane & 15, zq = lane >> 4;
  const int ty = blockIdx.x, b = blockIdx.z;
  const int seg = blockIdx.y * 4 + w;        // 0..15, 8 x-steps each
  const int y0 = ty * 14 - 1;
  const int gy = y0 + yi;
  const int cy = min(127, max(0, gy));       // clamp == dup col: max-safe
  const int x0 = seg * 8;
  const bool emit_ok = (yi >= 1) && (yi <= 14) && (gy <= 127);
  const float* __restrict__ col =
      in + ((size_t)b << 20) + ((size_t)cy << 6) + (zq << 4);

  int wcnt = 0;  // wave-uniform candidate count (scalar)
  float vC[16], vN[16], vT[16], pm[16], zmLast[16], zmN[16];

  auto loadv = [&](int x, float* v) {
    const int cx = min(127, max(0, x));
    const float4* p = (const float4*)(col + ((size_t)cx << 13));
    float4 a = p[0], bb = p[1], c = p[2], d = p[3];
    v[0] = a.x;  v[1] = a.y;  v[2] = a.z;  v[3] = a.w;
    v[4] = bb.x; v[5] = bb.y; v[6] = bb.z; v[7] = bb.w;
    v[8] = c.x;  v[9] = c.y;  v[10] = c.z; v[11] = c.w;
    v[12] = d.x; v[13] = d.y; v[14] = d.z; v[15] = d.w;
  };
  // z-stage: stripe-internal max3; boundaries via 2 shuffles (lane+-16 =
  // same yi, zq+-1); zq edges (z=-1 / z=64) forced to -inf.
  auto zmcalc = [&](const float* v, float* zm) {
    float vl = __shfl_up(v[15], 16, 64);
    float vr = __shfl_down(v[0], 16, 64);
    vl = (zq == 0) ? -1e30f : vl;
    vr = (zq == 3) ? -1e30f : vr;
    zm[0] = fmaxf(vl, fmaxf(v[0], v[1]));
#pragma unroll
    for (int j = 1; j < 15; ++j)
      zm[j] = fmaxf(v[j - 1], fmaxf(v[j], v[j + 1]));
    zm[15] = fmaxf(v[14], fmaxf(v[15], vr));
  };

  // Prologue: pm = max(zm(x0-1), zm(x0)); zmLast = zm(x0);
  //           vC = v(x0); vN = v(x0+1).
  loadv(x0 - 1, vT);
  zmcalc(vT, zmN);                // zm(x0-1) in zmN temp
  loadv(x0, vC);
  zmcalc(vC, zmLast);             // zm(x0)
#pragma unroll
  for (int j = 0; j < 16; ++j) pm[j] = fmaxf(zmN[j], zmLast[j]);
  loadv(x0 + 1, vN);

#pragma unroll 1
  for (int t = 0; t < 8; ++t) {
    const int x = x0 + t;
    if (t < 7) loadv(x + 2, vT);  // prefetch one plane ahead
    zmcalc(vN, zmN);              // zm(x+1)
#pragma unroll
    for (int j = 0; j < 16; ++j) {
      float xm = fmaxf(pm[j], zmN[j]);     // max over zm(x-1),zm(x),zm(x+1)
      float l = dpp_nbr_a(xm);             // y-neighbors via DPP
      float r = dpp_nbr_b(xm);
      float m27 = fmaxf(xm, fmaxf(l, r));
      float v = vC[j];
      const bool pred = emit_ok && (v >= m27);  // v == 27-max (self-incl.)
      u64 mask = __ballot(pred);
      if (pred) {
        unsigned g = ((unsigned)x << 13) | ((unsigned)gy << 6) |
                     (unsigned)((zq << 4) + j);
        u64 key = ((u64)__float_as_uint(v) << 32) | (u64)(unsigned)(~g);
        int ofs = __builtin_amdgcn_mbcnt_hi(
            (unsigned)(mask >> 32),
            __builtin_amdgcn_mbcnt_lo((unsigned)mask, 0));
        int slot = wcnt + ofs;
        if (slot < WCAP) cand[w][slot] = key;
      }
      wcnt += (int)__popcll(mask);
    }
    // rotate state (fixed-index, stays in registers)
#pragma unroll
    for (int j = 0; j < 16; ++j) {
      pm[j] = fmaxf(zmLast[j], zmN[j]);
      zmLast[j] = zmN[j];
      vC[j] = vN[j];
      vN[j] = vT[j];
    }
  }

  // ---- wave top-10 from LDS list (regs + butterfly, no barriers) ----
  __builtin_amdgcn_s_waitcnt(0);  // drain own-wave LDS writes
  const int count = min(wcnt, WCAP);
  u64 c[WCAP / 64];
#pragma unroll
  for (int i = 0; i < WCAP / 64; ++i) {
    int idx = lane + (i << 6);
    c[i] = (idx < count) ? cand[w][idx] : 0;
  }
  u64 mine = 0;
#pragma unroll 1
  for (int r = 0; r < NK; ++r) {
    u64 best = c[0];
#pragma unroll
    for (int i = 1; i < WCAP / 64; ++i) best = (c[i] > best) ? c[i] : best;
    u64 m = bfly_max_u64(best);
    if (m != 0 && best == m) {  // unique keys: only owner lane matches
#pragma unroll
      for (int i = 0; i < WCAP / 64; ++i)
        if (c[i] == m) c[i] = 0;
    }
    if (lane == r) mine = m;
  }
  if (lane < NK) wtop[w * NK + lane] = mine;
  __syncthreads();

  // ---- block merge 40 -> 10 (wave 0), one barrier total ----
  if (w == 0) {
    u64 c0 = (lane < 4 * NK) ? wtop[lane] : 0;
    u64 mv = 0;
#pragma unroll 1
    for (int r = 0; r < NK; ++r) {
      u64 m = bfly_max_u64(c0);
      if (m != 0 && c0 == m) c0 = 0;
      if (lane == r) mv = m;
    }
    if (lane < NK) {
      const int bi = blockIdx.y * TY + ty;  // 0..39 within batch
      part[((size_t)b * BLOCKS_PER_B + bi) * NK + lane] = mv;
    }
  }
}

// One wave per batch: 400 keys -> 7 regs/lane -> 10 butterfly rounds.
// Zero barriers, zero LDS.
__global__ __launch_bounds__(64) void final_select(
    const u64* __restrict__ part, float* __restrict__ out) {
  const int lane = threadIdx.x & 63;
  const int b = blockIdx.x;
  const int NKEY = BLOCKS_PER_B * NK;  // 400

  const u64* __restrict__ src = part + (size_t)b * NKEY;
  u64 c[7];
#pragma unroll
  for (int i = 0; i < 7; ++i) {
    int idx = lane + (i << 6);
    c[i] = (idx < NKEY) ? src[idx] : 0;
  }
  u64 mine = 0;
#pragma unroll 1
  for (int r = 0; r < NK; ++r) {
    u64 best = c[0];
#pragma unroll
    for (int i = 1; i < 7; ++i) best = (c[i] > best) ? c[i] : best;
    u64 m = bfly_max_u64(best);
    if (m != 0 && best == m) {
#pragma unroll
      for (int i = 0; i < 7; ++i)
        if (c[i] == m) c[i] = 0;
    }
    if (lane == r) mine = m;
  }
  if (lane < NK) {
    float val = 0.0f;
    unsigned g = 0u;
    if (mine != 0) {
      val = __uint_as_float((unsigned)(mine >> 32));
      g = ~((unsigned)mine);
    }
    float fx = (float)(g >> 13) * (8000.0f / 127.0f) - 4000.0f;
    float fy = (float)((g >> 6) & 127u) * (8000.0f / 127.0f) - 4000.0f;
    float fz = (float)(g & 63u) * (2000.0f / 63.0f) - 700.0f;
    float conf = (val > 0.3f) ? 0.0f : -1.0f;
    float* o = out + ((size_t)b * NK + lane) * 5;
    o[0] = fx; o[1] = fy; o[2] = fz; o[3] = conf; o[4] = val;
  }
}

extern "C" void kernel_launch(void* const* d_in, const int* in_sizes, int n_in,
                              void* d_out, int out_size, void* d_ws, size_t ws_size,
                              hipStream_t stream) {
  const float* in = (const float*)d_in[0];
  float* out = (float*)d_out;
  u64* part = (u64*)d_ws;  // 102,400 B used

  const int B = in_sizes[0] >> 20;  // 128*128*64 = 2^20 elements per batch
  dim3 gridA(TY, 4, (unsigned)B);
  peaks_topk<<<gridA, dim3(TPB), 0, stream>>>(in, part);
  final_select<<<dim3((unsigned)B), dim3(64), 0, stream>>>(part, out);
}